// Round 6
// baseline (385.711 us; speedup 1.0000x reference)
//
#include <hip/hip_runtime.h>

// Problem constants (from reference):
//   EDGE=255, ADD=127, AX=382 -> input (16,32,382,255) f32
//   S = 2*382+1 = 765 -> output tensor (16,32,765,765) f32
//   plus u_min/u_max/v_min/v_max, 16 each, written as float values.
namespace {
constexpr int kB = 16;
constexpr int kC = 32;
constexpr int kH = 382;   // AX
constexpr int kW = 255;   // EDGE
constexpr int kS = 765;   // 2*H+1
constexpr unsigned kPlane = (unsigned)kS * (unsigned)kS;            // 585225
constexpr unsigned long long kOutElems =
    (unsigned long long)kB * kC * (unsigned long long)kPlane;       // 299,635,200
constexpr unsigned kNVec = (unsigned)(kOutElems / 4ull);            // 74,908,800
}

// Gather formulation: out[b][c][u][v] = in[b][c][u+du][v+dv] if in range else 0
// du = (q - r/2) - 255, dv = r - 382.
__global__ __launch_bounds__(256) void axial_gather_kernel(
    const float* __restrict__ in, const int* __restrict__ off,
    float* __restrict__ out)
{
    unsigned t = blockIdx.x * 256u + threadIdx.x;
    if (t >= kNVec) return;
    unsigned idx = t * 4u;                    // flat element index, fits in u32

    unsigned plane = idx / kPlane;            // const-div -> mulhi
    unsigned rem   = idx - plane * kPlane;
    unsigned u     = rem / (unsigned)kS;
    unsigned v     = rem - u * (unsigned)kS;
    unsigned c     = plane & 31u;
    unsigned b     = plane >> 5;

    int q = off[2u * b];
    int r = off[2u * b + 1u];
    int du = (q - (r >> 1)) - 255;
    int dv = r - 382;

    float4 res;
    float* rp = reinterpret_cast<float*>(&res);

#pragma unroll
    for (int k = 0; k < 4; ++k) {
        int h = (int)u + du;
        int w = (int)v + dv;
        float val = 0.0f;
        if ((unsigned)h < (unsigned)kH && (unsigned)w < (unsigned)kW) {
            val = in[(((size_t)b * kC + c) * kH + (unsigned)h) * (size_t)kW
                     + (unsigned)w];
        }
        rp[k] = val;
        if (k < 3) {
            // advance to next flat element (row / plane carries; b-boundaries
            // are 4-aligned so the b-reload is effectively dead but safe)
            if (++v == (unsigned)kS) {
                v = 0u;
                if (++u == (unsigned)kS) {
                    u = 0u;
                    if (++c == (unsigned)kC) {
                        c = 0u;
                        ++b;
                        if (b < (unsigned)kB) {
                            q = off[2u * b];
                            r = off[2u * b + 1u];
                            du = (q - (r >> 1)) - 255;
                            dv = r - 382;
                        }
                    }
                }
            }
        }
    }
    reinterpret_cast<float4*>(out)[t] = res;
}

// u_min = 255 - uoff ; u_max = u_min + 382 ; v_min = 382 - r ; v_max = v_min + 255
__global__ void axial_extras_kernel(const int* __restrict__ off,
                                    float* __restrict__ out_tail)
{
    int i = threadIdx.x;          // 0..63
    if (i >= 64) return;
    int b = i & 15;
    int which = i >> 4;           // 0:u_min 1:u_max 2:v_min 3:v_max
    int q = off[2 * b];
    int r = off[2 * b + 1];
    int uoff = q - (r >> 1);
    int u_min = 255 - uoff;
    int v_min = 382 - r;
    int val = (which == 0) ? u_min
            : (which == 1) ? (u_min + kH)
            : (which == 2) ? v_min
                           : (v_min + kW);
    out_tail[i] = (float)val;
}

extern "C" void kernel_launch(void* const* d_in, const int* in_sizes, int n_in,
                              void* d_out, int out_size, void* d_ws, size_t ws_size,
                              hipStream_t stream) {
    const float* in  = (const float*)d_in[0];
    const int*   off = (const int*)d_in[1];
    float*       out = (float*)d_out;

    unsigned blocks = (kNVec + 255u) / 256u;
    axial_gather_kernel<<<dim3(blocks), dim3(256), 0, stream>>>(in, off, out);
    axial_extras_kernel<<<dim3(1), dim3(64), 0, stream>>>(off, out + kOutElems);
}